// Round 1
// baseline (562.668 us; speedup 1.0000x reference)
//
#include <hip/hip_runtime.h>
#include <math.h>

#define ALPHA_C 0.5f
#define BETA_C  0.5f
#define NPART   256

__global__ __launch_bounds__(256) void k_degrees(
        const int* __restrict__ eidx, float* __restrict__ deg_out,
        float* __restrict__ deg_in, int E) {
    int i = blockIdx.x * blockDim.x + threadIdx.x;
    if (i < E) {
        atomicAdd(&deg_out[eidx[i]], 1.0f);       // src out-degree
        atomicAdd(&deg_in[eidx[E + i]], 1.0f);    // dst in-degree
    }
}

__global__ __launch_bounds__(256) void k_sumsq(
        const float* __restrict__ deg_out, const float* __restrict__ deg_in,
        float* __restrict__ partials, int N) {
    float so = 0.f, si = 0.f;
    for (int i = blockIdx.x * blockDim.x + threadIdx.x; i < N;
         i += gridDim.x * blockDim.x) {
        float a = deg_out[i], b = deg_in[i];
        so = fmaf(a, a, so);
        si = fmaf(b, b, si);
    }
#pragma unroll
    for (int off = 32; off; off >>= 1) {
        so += __shfl_xor(so, off);
        si += __shfl_xor(si, off);
    }
    __shared__ float sm[2][4];
    int lane = threadIdx.x & 63, w = threadIdx.x >> 6;
    if (lane == 0) { sm[0][w] = so; sm[1][w] = si; }
    __syncthreads();
    if (threadIdx.x == 0) {
        partials[blockIdx.x]         = sm[0][0] + sm[0][1] + sm[0][2] + sm[0][3];
        partials[NPART + blockIdx.x] = sm[1][0] + sm[1][1] + sm[1][2] + sm[1][3];
    }
}

__global__ __launch_bounds__(256) void k_finish(
        const float* __restrict__ partials, float* __restrict__ inv_nrm) {
    int t = threadIdx.x;
    float so = partials[t], si = partials[NPART + t];
#pragma unroll
    for (int off = 32; off; off >>= 1) {
        so += __shfl_xor(so, off);
        si += __shfl_xor(si, off);
    }
    __shared__ float sm[2][4];
    int lane = t & 63, w = t >> 6;
    if (lane == 0) { sm[0][w] = so; sm[1][w] = si; }
    __syncthreads();
    if (t == 0) {
        float a = sm[0][0] + sm[0][1] + sm[0][2] + sm[0][3];
        float b = sm[1][0] + sm[1][1] + sm[1][2] + sm[1][3];
        inv_nrm[0] = (a > 0.f) ? rsqrtf(a) : 0.f;
        inv_nrm[1] = (b > 0.f) ? rsqrtf(b) : 0.f;
    }
}

// Per-node precompute: v_out = W_out^T z_out[:, :64], v_in = W_in^T z_in[:, :64],
// plus the per-node scalar terms. One wave per node; W held in registers.
__global__ __launch_bounds__(256) void k_nodes(
        const float* __restrict__ z_in, const float* __restrict__ z_out,
        const float* __restrict__ W_in, const float* __restrict__ b_in,
        const float* __restrict__ W_out, const float* __restrict__ b_out,
        const float* __restrict__ deg_out, const float* __restrict__ deg_in,
        const float* __restrict__ inv_nrm,
        float* __restrict__ v_out, float* __restrict__ v_in,
        float* __restrict__ s_src, float* __restrict__ s_dst, int N) {
    const int lane = threadIdx.x & 63;
    const int gw = (blockIdx.x * blockDim.x + threadIdx.x) >> 6;
    const int nw = (gridDim.x * blockDim.x) >> 6;
    float wo[64], wi[64];
#pragma unroll
    for (int d = 0; d < 64; ++d) {
        wo[d] = W_out[d * 64 + lane];   // column `lane` of W_out
        wi[d] = W_in[d * 64 + lane];
    }
    const float bo = b_out[lane], bi = b_in[lane];
    const float inv0 = inv_nrm[0], inv1 = inv_nrm[1];
    for (int n = gw; n < N; n += nw) {
        const float zo = z_out[(size_t)n * 65 + lane];
        const float zi = z_in[(size_t)n * 65 + lane];
        float ao = 0.f, ai = 0.f;
#pragma unroll
        for (int d = 0; d < 64; ++d) {
            ao = fmaf(wo[d], __shfl(zo, d), ao);
            ai = fmaf(wi[d], __shfl(zi, d), ai);
        }
        v_out[(size_t)n * 64 + lane] = ao;
        v_in[(size_t)n * 64 + lane] = ai;
        float so = zo * bo, si = zi * bi;
#pragma unroll
        for (int off = 32; off; off >>= 1) {
            so += __shfl_xor(so, off);
            si += __shfl_xor(si, off);
        }
        if (lane == 0) {
            s_src[n] = BETA_C * fmaf(deg_out[n], inv0, z_out[(size_t)n * 65 + 64])
                     + ALPHA_C * so;
            s_dst[n] = BETA_C * fmaf(deg_in[n], inv1, z_in[(size_t)n * 65 + 64])
                     + ALPHA_C * si;
        }
    }
}

// Per-edge: 16 lanes/edge, two 64-float dots via float4 gathers + shfl reduce.
__global__ __launch_bounds__(256) void k_edges(
        const int* __restrict__ eidx,
        const float* __restrict__ z_self, const float* __restrict__ v_out,
        const float* __restrict__ v_in, const float* __restrict__ s_src,
        const float* __restrict__ s_dst, float* __restrict__ out, int E) {
    const int sub = threadIdx.x & 15;
    const int e = blockIdx.x * (blockDim.x >> 4) + (threadIdx.x >> 4);
    if (e >= E) return;
    const int s = eidx[e];
    const int d = eidx[E + e];
    const float4 a = ((const float4*)(v_out + (size_t)s * 64))[sub];
    const float4 b = ((const float4*)(z_self + (size_t)d * 64))[sub];
    const float4 c = ((const float4*)(z_self + (size_t)s * 64))[sub];
    const float4 f = ((const float4*)(v_in + (size_t)d * 64))[sub];
    float acc = a.x * b.x + a.y * b.y + a.z * b.z + a.w * b.w
              + c.x * f.x + c.y * f.y + c.z * f.z + c.w * f.w;
    acc += __shfl_xor(acc, 8);
    acc += __shfl_xor(acc, 4);
    acc += __shfl_xor(acc, 2);
    acc += __shfl_xor(acc, 1);
    if (sub == 0) {
        float v = fmaf(ALPHA_C, acc, s_src[s] + s_dst[d]);
        out[e] = 1.0f / (1.0f + __expf(-v));
    }
}

extern "C" void kernel_launch(void* const* d_in, const int* in_sizes, int n_in,
                              void* d_out, int out_size, void* d_ws, size_t ws_size,
                              hipStream_t stream) {
    const float* z_in   = (const float*)d_in[0];
    const float* z_out  = (const float*)d_in[1];
    const float* z_self = (const float*)d_in[2];
    const float* W_in   = (const float*)d_in[3];
    const float* b_in   = (const float*)d_in[4];
    const float* W_out  = (const float*)d_in[5];
    const float* b_out  = (const float*)d_in[6];
    const int*   eidx   = (const int*)d_in[7];

    const int N = in_sizes[2] / 64;   // z_self is [N, 64]
    const int E = in_sizes[7] / 2;    // edge_index is [2, E]

    float* ws       = (float*)d_ws;
    float* deg_out  = ws;                             // N
    float* deg_in   = ws + (size_t)N;                 // N
    float* s_src    = ws + 2 * (size_t)N;             // N
    float* s_dst    = ws + 3 * (size_t)N;             // N
    float* v_out    = ws + 4 * (size_t)N;             // N*64
    float* v_in     = v_out + (size_t)N * 64;         // N*64
    float* partials = v_in + (size_t)N * 64;          // 2*NPART
    float* inv_nrm  = partials + 2 * NPART;           // 2

    hipMemsetAsync(deg_out, 0, 2 * (size_t)N * sizeof(float), stream);
    k_degrees<<<(E + 255) / 256, 256, 0, stream>>>(eidx, deg_out, deg_in, E);
    k_sumsq<<<NPART, 256, 0, stream>>>(deg_out, deg_in, partials, N);
    k_finish<<<1, 256, 0, stream>>>(partials, inv_nrm);
    k_nodes<<<1024, 256, 0, stream>>>(z_in, z_out, W_in, b_in, W_out, b_out,
                                      deg_out, deg_in, inv_nrm,
                                      v_out, v_in, s_src, s_dst, N);
    k_edges<<<(E + 15) / 16, 256, 0, stream>>>(eidx, z_self, v_out, v_in,
                                               s_src, s_dst, (float*)d_out, E);
}

// Round 2
// 451.384 us; speedup vs baseline: 1.2465x; 1.2465x over previous
//
#include <hip/hip_runtime.h>
#include <hip/hip_fp16.h>
#include <math.h>

#define ALPHA_C 0.5f
#define BETA_C  0.5f
#define NPART   256

typedef _Float16 half8 __attribute__((ext_vector_type(8)));

__global__ __launch_bounds__(256) void k_degrees(
        const int* __restrict__ eidx, float* __restrict__ deg_out,
        float* __restrict__ deg_in, int E) {
    int i = blockIdx.x * blockDim.x + threadIdx.x;
    if (i < E) {
        atomicAdd(&deg_out[eidx[i]], 1.0f);       // src out-degree
        atomicAdd(&deg_in[eidx[E + i]], 1.0f);    // dst in-degree
    }
}

__global__ __launch_bounds__(256) void k_sumsq(
        const float* __restrict__ deg_out, const float* __restrict__ deg_in,
        float* __restrict__ partials, int N) {
    float so = 0.f, si = 0.f;
    for (int i = blockIdx.x * blockDim.x + threadIdx.x; i < N;
         i += gridDim.x * blockDim.x) {
        float a = deg_out[i], b = deg_in[i];
        so = fmaf(a, a, so);
        si = fmaf(b, b, si);
    }
#pragma unroll
    for (int off = 32; off; off >>= 1) {
        so += __shfl_xor(so, off);
        si += __shfl_xor(si, off);
    }
    __shared__ float sm[2][4];
    int lane = threadIdx.x & 63, w = threadIdx.x >> 6;
    if (lane == 0) { sm[0][w] = so; sm[1][w] = si; }
    __syncthreads();
    if (threadIdx.x == 0) {
        partials[blockIdx.x]         = sm[0][0] + sm[0][1] + sm[0][2] + sm[0][3];
        partials[NPART + blockIdx.x] = sm[1][0] + sm[1][1] + sm[1][2] + sm[1][3];
    }
}

__global__ __launch_bounds__(256) void k_finish(
        const float* __restrict__ partials, float* __restrict__ inv_nrm) {
    int t = threadIdx.x;
    float so = partials[t], si = partials[NPART + t];
#pragma unroll
    for (int off = 32; off; off >>= 1) {
        so += __shfl_xor(so, off);
        si += __shfl_xor(si, off);
    }
    __shared__ float sm[2][4];
    int lane = t & 63, w = t >> 6;
    if (lane == 0) { sm[0][w] = so; sm[1][w] = si; }
    __syncthreads();
    if (t == 0) {
        float a = sm[0][0] + sm[0][1] + sm[0][2] + sm[0][3];
        float b = sm[1][0] + sm[1][1] + sm[1][2] + sm[1][3];
        inv_nrm[0] = (a > 0.f) ? rsqrtf(a) : 0.f;
        inv_nrm[1] = (b > 0.f) ? rsqrtf(b) : 0.f;
    }
}

// Per-node precompute. One wave per node; W columns held in registers.
// Emits packed fp16 gather rows:
//   P_src[n] = [ W_out^T z_out[n,:64] | z_self[n] ]   (128 fp16 = 256 B)
//   P_dst[n] = [ z_self[n] | W_in^T z_in[n,:64] ]
// so the per-edge value is a single 128-dot P_src[s]·P_dst[d].
__global__ __launch_bounds__(256) void k_nodes(
        const float* __restrict__ z_in, const float* __restrict__ z_out,
        const float* __restrict__ z_self,
        const float* __restrict__ W_in, const float* __restrict__ b_in,
        const float* __restrict__ W_out, const float* __restrict__ b_out,
        const float* __restrict__ deg_out, const float* __restrict__ deg_in,
        const float* __restrict__ inv_nrm,
        _Float16* __restrict__ P_src, _Float16* __restrict__ P_dst,
        float* __restrict__ s_src, float* __restrict__ s_dst, int N) {
    const int lane = threadIdx.x & 63;
    const int gw = (blockIdx.x * blockDim.x + threadIdx.x) >> 6;
    const int nw = (gridDim.x * blockDim.x) >> 6;
    float wo[64], wi[64];
#pragma unroll
    for (int d = 0; d < 64; ++d) {
        wo[d] = W_out[d * 64 + lane];   // column `lane` of W_out
        wi[d] = W_in[d * 64 + lane];
    }
    const float bo = b_out[lane], bi = b_in[lane];
    const float inv0 = inv_nrm[0], inv1 = inv_nrm[1];
    for (int n = gw; n < N; n += nw) {
        const float zo = z_out[(size_t)n * 65 + lane];
        const float zi = z_in[(size_t)n * 65 + lane];
        const float zs = z_self[(size_t)n * 64 + lane];
        float ao = 0.f, ai = 0.f;
#pragma unroll
        for (int d = 0; d < 64; ++d) {
            ao = fmaf(wo[d], __shfl(zo, d), ao);
            ai = fmaf(wi[d], __shfl(zi, d), ai);
        }
        P_src[(size_t)n * 128 + lane]      = (_Float16)ao;
        P_src[(size_t)n * 128 + 64 + lane] = (_Float16)zs;
        P_dst[(size_t)n * 128 + lane]      = (_Float16)zs;
        P_dst[(size_t)n * 128 + 64 + lane] = (_Float16)ai;
        float so = zo * bo, si = zi * bi;
#pragma unroll
        for (int off = 32; off; off >>= 1) {
            so += __shfl_xor(so, off);
            si += __shfl_xor(si, off);
        }
        if (lane == 0) {
            s_src[n] = BETA_C * fmaf(deg_out[n], inv0, z_out[(size_t)n * 65 + 64])
                     + ALPHA_C * so;
            s_dst[n] = BETA_C * fmaf(deg_in[n], inv1, z_in[(size_t)n * 65 + 64])
                     + ALPHA_C * si;
        }
    }
}

// Per-edge: 16 lanes/edge, one 128-length fp16 dot via two 16B gathers/lane.
__global__ __launch_bounds__(256) void k_edges(
        const int* __restrict__ eidx,
        const _Float16* __restrict__ P_src, const _Float16* __restrict__ P_dst,
        const float* __restrict__ s_src, const float* __restrict__ s_dst,
        float* __restrict__ out, int E) {
    const int sub = threadIdx.x & 15;
    const int e = blockIdx.x * (blockDim.x >> 4) + (threadIdx.x >> 4);
    if (e >= E) return;
    const int s = eidx[e];
    const int d = eidx[E + e];
    const half8 a = *(const half8*)(P_src + (size_t)s * 128 + sub * 8);
    const half8 b = *(const half8*)(P_dst + (size_t)d * 128 + sub * 8);
    float acc = 0.f;
#pragma unroll
    for (int j = 0; j < 8; ++j)
        acc = fmaf((float)a[j], (float)b[j], acc);
    acc += __shfl_xor(acc, 8);
    acc += __shfl_xor(acc, 4);
    acc += __shfl_xor(acc, 2);
    acc += __shfl_xor(acc, 1);
    if (sub == 0) {
        float v = fmaf(ALPHA_C, acc, s_src[s] + s_dst[d]);
        out[e] = 1.0f / (1.0f + __expf(-v));
    }
}

extern "C" void kernel_launch(void* const* d_in, const int* in_sizes, int n_in,
                              void* d_out, int out_size, void* d_ws, size_t ws_size,
                              hipStream_t stream) {
    const float* z_in   = (const float*)d_in[0];
    const float* z_out  = (const float*)d_in[1];
    const float* z_self = (const float*)d_in[2];
    const float* W_in   = (const float*)d_in[3];
    const float* b_in   = (const float*)d_in[4];
    const float* W_out  = (const float*)d_in[5];
    const float* b_out  = (const float*)d_in[6];
    const int*   eidx   = (const int*)d_in[7];

    const int N = in_sizes[2] / 64;   // z_self is [N, 64]
    const int E = in_sizes[7] / 2;    // edge_index is [2, E]

    float* ws       = (float*)d_ws;
    float* deg_out  = ws;                             // N
    float* deg_in   = ws + (size_t)N;                 // N
    float* s_src    = ws + 2 * (size_t)N;             // N
    float* s_dst    = ws + 3 * (size_t)N;             // N
    _Float16* P_src = (_Float16*)(ws + 4 * (size_t)N);        // N*128 fp16
    _Float16* P_dst = P_src + (size_t)N * 128;                // N*128 fp16
    float* partials = (float*)(P_dst + (size_t)N * 128);      // 2*NPART
    float* inv_nrm  = partials + 2 * NPART;                   // 2

    hipMemsetAsync(deg_out, 0, 2 * (size_t)N * sizeof(float), stream);
    k_degrees<<<(E + 255) / 256, 256, 0, stream>>>(eidx, deg_out, deg_in, E);
    k_sumsq<<<NPART, 256, 0, stream>>>(deg_out, deg_in, partials, N);
    k_finish<<<1, 256, 0, stream>>>(partials, inv_nrm);
    k_nodes<<<1024, 256, 0, stream>>>(z_in, z_out, z_self, W_in, b_in, W_out, b_out,
                                      deg_out, deg_in, inv_nrm,
                                      P_src, P_dst, s_src, s_dst, N);
    k_edges<<<(E + 15) / 16, 256, 0, stream>>>(eidx, P_src, P_dst,
                                               s_src, s_dst, (float*)d_out, E);
}

// Round 3
// 376.411 us; speedup vs baseline: 1.4948x; 1.1992x over previous
//
#include <hip/hip_runtime.h>
#include <hip/hip_fp16.h>
#include <math.h>

#define ALPHA_C 0.5f
#define BETA_C  0.5f
#define NPART   256

typedef _Float16 half8 __attribute__((ext_vector_type(8)));

__global__ __launch_bounds__(256) void k_degrees(
        const int* __restrict__ eidx, float* __restrict__ deg_out,
        float* __restrict__ deg_in, int E) {
    int i = blockIdx.x * blockDim.x + threadIdx.x;
    int E4 = E >> 2;
    if (i < E4) {
        int4 s = ((const int4*)eidx)[i];
        atomicAdd(&deg_out[s.x], 1.0f);
        atomicAdd(&deg_out[s.y], 1.0f);
        atomicAdd(&deg_out[s.z], 1.0f);
        atomicAdd(&deg_out[s.w], 1.0f);
        int4 d = ((const int4*)(eidx + E))[i];
        atomicAdd(&deg_in[d.x], 1.0f);
        atomicAdd(&deg_in[d.y], 1.0f);
        atomicAdd(&deg_in[d.z], 1.0f);
        atomicAdd(&deg_in[d.w], 1.0f);
    }
    // tail (E not divisible by 4)
    int t = E4 * 4 + i;
    if (i < (E & 3)) {
        atomicAdd(&deg_out[eidx[t]], 1.0f);
        atomicAdd(&deg_in[eidx[E + t]], 1.0f);
    }
}

__global__ __launch_bounds__(256) void k_sumsq(
        const float* __restrict__ deg_out, const float* __restrict__ deg_in,
        float* __restrict__ partials, int N) {
    float so = 0.f, si = 0.f;
    for (int i = blockIdx.x * blockDim.x + threadIdx.x; i < N;
         i += gridDim.x * blockDim.x) {
        float a = deg_out[i], b = deg_in[i];
        so = fmaf(a, a, so);
        si = fmaf(b, b, si);
    }
#pragma unroll
    for (int off = 32; off; off >>= 1) {
        so += __shfl_xor(so, off);
        si += __shfl_xor(si, off);
    }
    __shared__ float sm[2][4];
    int lane = threadIdx.x & 63, w = threadIdx.x >> 6;
    if (lane == 0) { sm[0][w] = so; sm[1][w] = si; }
    __syncthreads();
    if (threadIdx.x == 0) {
        partials[blockIdx.x]         = sm[0][0] + sm[0][1] + sm[0][2] + sm[0][3];
        partials[NPART + blockIdx.x] = sm[1][0] + sm[1][1] + sm[1][2] + sm[1][3];
    }
}

__global__ __launch_bounds__(256) void k_finish(
        const float* __restrict__ partials, float* __restrict__ inv_nrm) {
    int t = threadIdx.x;
    float so = partials[t], si = partials[NPART + t];
#pragma unroll
    for (int off = 32; off; off >>= 1) {
        so += __shfl_xor(so, off);
        si += __shfl_xor(si, off);
    }
    __shared__ float sm[2][4];
    int lane = t & 63, w = t >> 6;
    if (lane == 0) { sm[0][w] = so; sm[1][w] = si; }
    __syncthreads();
    if (t == 0) {
        float a = sm[0][0] + sm[0][1] + sm[0][2] + sm[0][3];
        float b = sm[1][0] + sm[1][1] + sm[1][2] + sm[1][3];
        inv_nrm[0] = (a > 0.f) ? rsqrtf(a) : 0.f;
        inv_nrm[1] = (b > 0.f) ? rsqrtf(b) : 0.f;
    }
}

// Per-node precompute, one wave per node. W columns live in VGPRs; the
// broadcast z[n][d] values are wave-uniform and read through the SCALAR
// path (readfirstlane(n) -> s_load), so the inner loop is pure
// v_fma_f32(v, s, v) with no ds_bpermute chain.
__global__ __launch_bounds__(256) void k_nodes(
        const float* __restrict__ z_in, const float* __restrict__ z_out,
        const float* __restrict__ z_self,
        const float* __restrict__ W_in, const float* __restrict__ b_in,
        const float* __restrict__ W_out, const float* __restrict__ b_out,
        const float* __restrict__ deg_out, const float* __restrict__ deg_in,
        const float* __restrict__ inv_nrm,
        _Float16* __restrict__ P_src, _Float16* __restrict__ P_dst,
        float* __restrict__ s_src, float* __restrict__ s_dst, int N) {
    const int lane = threadIdx.x & 63;
    const int gw0 = (blockIdx.x * blockDim.x + threadIdx.x) >> 6;
    const int nw = (gridDim.x * blockDim.x) >> 6;
    float wo[64], wi[64];
#pragma unroll
    for (int d = 0; d < 64; ++d) {
        wo[d] = W_out[d * 64 + lane];   // column `lane` of W_out
        wi[d] = W_in[d * 64 + lane];
    }
    const float bo = b_out[lane], bi = b_in[lane];
    const float inv0 = inv_nrm[0], inv1 = inv_nrm[1];
    for (int n0 = gw0; n0 < N; n0 += nw) {
        const int n = __builtin_amdgcn_readfirstlane(n0);   // wave-uniform
        const float* __restrict__ zro = z_out + (size_t)n * 65;
        const float* __restrict__ zri = z_in + (size_t)n * 65;
        const float zo = zro[lane];                  // per-lane (vector load)
        const float zi = zri[lane];
        const float zs = z_self[(size_t)n * 64 + lane];
        float ao = 0.f, ai = 0.f;
#pragma unroll
        for (int d = 0; d < 64; ++d) {               // zro[d]/zri[d]: s_load
            ao = fmaf(wo[d], zro[d], ao);
            ai = fmaf(wi[d], zri[d], ai);
        }
        P_src[(size_t)n * 128 + lane]      = (_Float16)ao;
        P_src[(size_t)n * 128 + 64 + lane] = (_Float16)zs;
        P_dst[(size_t)n * 128 + lane]      = (_Float16)zs;
        P_dst[(size_t)n * 128 + 64 + lane] = (_Float16)ai;
        float so = zo * bo, si = zi * bi;
#pragma unroll
        for (int off = 32; off; off >>= 1) {
            so += __shfl_xor(so, off);
            si += __shfl_xor(si, off);
        }
        if (lane == 0) {
            s_src[n] = BETA_C * fmaf(deg_out[n], inv0, zro[64])
                     + ALPHA_C * so;
            s_dst[n] = BETA_C * fmaf(deg_in[n], inv1, zri[64])
                     + ALPHA_C * si;
        }
    }
}

// Per-edge: 16 lanes/edge, one 128-length fp16 dot via two 16B gathers/lane.
__global__ __launch_bounds__(256) void k_edges(
        const int* __restrict__ eidx,
        const _Float16* __restrict__ P_src, const _Float16* __restrict__ P_dst,
        const float* __restrict__ s_src, const float* __restrict__ s_dst,
        float* __restrict__ out, int E) {
    const int sub = threadIdx.x & 15;
    const int e = blockIdx.x * (blockDim.x >> 4) + (threadIdx.x >> 4);
    if (e >= E) return;
    const int s = eidx[e];
    const int d = eidx[E + e];
    const half8 a = *(const half8*)(P_src + (size_t)s * 128 + sub * 8);
    const half8 b = *(const half8*)(P_dst + (size_t)d * 128 + sub * 8);
    float acc = 0.f;
#pragma unroll
    for (int j = 0; j < 8; ++j)
        acc = fmaf((float)a[j], (float)b[j], acc);
    acc += __shfl_xor(acc, 8);
    acc += __shfl_xor(acc, 4);
    acc += __shfl_xor(acc, 2);
    acc += __shfl_xor(acc, 1);
    if (sub == 0) {
        float v = fmaf(ALPHA_C, acc, s_src[s] + s_dst[d]);
        out[e] = 1.0f / (1.0f + __expf(-v));
    }
}

extern "C" void kernel_launch(void* const* d_in, const int* in_sizes, int n_in,
                              void* d_out, int out_size, void* d_ws, size_t ws_size,
                              hipStream_t stream) {
    const float* z_in   = (const float*)d_in[0];
    const float* z_out  = (const float*)d_in[1];
    const float* z_self = (const float*)d_in[2];
    const float* W_in   = (const float*)d_in[3];
    const float* b_in   = (const float*)d_in[4];
    const float* W_out  = (const float*)d_in[5];
    const float* b_out  = (const float*)d_in[6];
    const int*   eidx   = (const int*)d_in[7];

    const int N = in_sizes[2] / 64;   // z_self is [N, 64]
    const int E = in_sizes[7] / 2;    // edge_index is [2, E]

    float* ws       = (float*)d_ws;
    float* deg_out  = ws;                             // N
    float* deg_in   = ws + (size_t)N;                 // N
    float* s_src    = ws + 2 * (size_t)N;             // N
    float* s_dst    = ws + 3 * (size_t)N;             // N
    _Float16* P_src = (_Float16*)(ws + 4 * (size_t)N);        // N*128 fp16
    _Float16* P_dst = P_src + (size_t)N * 128;                // N*128 fp16
    float* partials = (float*)(P_dst + (size_t)N * 128);      // 2*NPART
    float* inv_nrm  = partials + 2 * NPART;                   // 2

    hipMemsetAsync(deg_out, 0, 2 * (size_t)N * sizeof(float), stream);
    k_degrees<<<(E / 4 + 255) / 256, 256, 0, stream>>>(eidx, deg_out, deg_in, E);
    k_sumsq<<<NPART, 256, 0, stream>>>(deg_out, deg_in, partials, N);
    k_finish<<<1, 256, 0, stream>>>(partials, inv_nrm);
    k_nodes<<<1024, 256, 0, stream>>>(z_in, z_out, z_self, W_in, b_in, W_out, b_out,
                                      deg_out, deg_in, inv_nrm,
                                      P_src, P_dst, s_src, s_dst, N);
    k_edges<<<(E + 15) / 16, 256, 0, stream>>>(eidx, P_src, P_dst,
                                               s_src, s_dst, (float*)d_out, E);
}

// Round 4
// 339.678 us; speedup vs baseline: 1.6565x; 1.1081x over previous
//
#include <hip/hip_runtime.h>
#include <hip/hip_fp16.h>
#include <math.h>

#define ALPHA_C 0.5f
#define BETA_C  0.5f
#define NPART   256
#define NXCD    8

typedef _Float16 half8 __attribute__((ext_vector_type(8)));

// Per-XCD partial degree histograms. Each workgroup reads its physical XCD id
// and updates that XCD's private counters with XCD-local (L2-resident) atomics,
// avoiding the fabric round-trip that device-scope atomics pay on gfx950.
__global__ __launch_bounds__(256) void k_degrees(
        const int* __restrict__ eidx, unsigned int* __restrict__ part,
        int N, int E) {
    unsigned int xcc;
    asm volatile("s_getreg_b32 %0, hwreg(HW_REG_XCC_ID)" : "=s"(xcc));
    unsigned int* __restrict__ po = part + (size_t)(xcc & (NXCD - 1)) * 2 * N;
    unsigned int* __restrict__ pi = po + N;
    int i = blockIdx.x * blockDim.x + threadIdx.x;
    int E4 = E >> 2;
    if (i < E4) {
        int4 s = ((const int4*)eidx)[i];
        __hip_atomic_fetch_add(&po[s.x], 1u, __ATOMIC_RELAXED, __HIP_MEMORY_SCOPE_WORKGROUP);
        __hip_atomic_fetch_add(&po[s.y], 1u, __ATOMIC_RELAXED, __HIP_MEMORY_SCOPE_WORKGROUP);
        __hip_atomic_fetch_add(&po[s.z], 1u, __ATOMIC_RELAXED, __HIP_MEMORY_SCOPE_WORKGROUP);
        __hip_atomic_fetch_add(&po[s.w], 1u, __ATOMIC_RELAXED, __HIP_MEMORY_SCOPE_WORKGROUP);
        int4 d = ((const int4*)(eidx + E))[i];
        __hip_atomic_fetch_add(&pi[d.x], 1u, __ATOMIC_RELAXED, __HIP_MEMORY_SCOPE_WORKGROUP);
        __hip_atomic_fetch_add(&pi[d.y], 1u, __ATOMIC_RELAXED, __HIP_MEMORY_SCOPE_WORKGROUP);
        __hip_atomic_fetch_add(&pi[d.z], 1u, __ATOMIC_RELAXED, __HIP_MEMORY_SCOPE_WORKGROUP);
        __hip_atomic_fetch_add(&pi[d.w], 1u, __ATOMIC_RELAXED, __HIP_MEMORY_SCOPE_WORKGROUP);
    }
    // tail (E not divisible by 4)
    int t = E4 * 4 + i;
    if (i < (E & 3)) {
        __hip_atomic_fetch_add(&po[eidx[t]], 1u, __ATOMIC_RELAXED, __HIP_MEMORY_SCOPE_WORKGROUP);
        __hip_atomic_fetch_add(&pi[eidx[E + t]], 1u, __ATOMIC_RELAXED, __HIP_MEMORY_SCOPE_WORKGROUP);
    }
}

// Fold the 8 partial histograms into final degrees, and reduce sums of squares.
__global__ __launch_bounds__(256) void k_sumsq(
        const unsigned int* __restrict__ part,
        float* __restrict__ deg_out, float* __restrict__ deg_in,
        float* __restrict__ partials, int N) {
    float so = 0.f, si = 0.f;
    for (int i = blockIdx.x * blockDim.x + threadIdx.x; i < N;
         i += gridDim.x * blockDim.x) {
        unsigned int a = 0, b = 0;
#pragma unroll
        for (int x = 0; x < NXCD; ++x) {
            a += part[(size_t)(2 * x) * N + i];
            b += part[(size_t)(2 * x + 1) * N + i];
        }
        float fa = (float)a, fb = (float)b;
        deg_out[i] = fa;
        deg_in[i] = fb;
        so = fmaf(fa, fa, so);
        si = fmaf(fb, fb, si);
    }
#pragma unroll
    for (int off = 32; off; off >>= 1) {
        so += __shfl_xor(so, off);
        si += __shfl_xor(si, off);
    }
    __shared__ float sm[2][4];
    int lane = threadIdx.x & 63, w = threadIdx.x >> 6;
    if (lane == 0) { sm[0][w] = so; sm[1][w] = si; }
    __syncthreads();
    if (threadIdx.x == 0) {
        partials[blockIdx.x]         = sm[0][0] + sm[0][1] + sm[0][2] + sm[0][3];
        partials[NPART + blockIdx.x] = sm[1][0] + sm[1][1] + sm[1][2] + sm[1][3];
    }
}

__global__ __launch_bounds__(256) void k_finish(
        const float* __restrict__ partials, float* __restrict__ inv_nrm) {
    int t = threadIdx.x;
    float so = partials[t], si = partials[NPART + t];
#pragma unroll
    for (int off = 32; off; off >>= 1) {
        so += __shfl_xor(so, off);
        si += __shfl_xor(si, off);
    }
    __shared__ float sm[2][4];
    int lane = t & 63, w = t >> 6;
    if (lane == 0) { sm[0][w] = so; sm[1][w] = si; }
    __syncthreads();
    if (t == 0) {
        float a = sm[0][0] + sm[0][1] + sm[0][2] + sm[0][3];
        float b = sm[1][0] + sm[1][1] + sm[1][2] + sm[1][3];
        inv_nrm[0] = (a > 0.f) ? rsqrtf(a) : 0.f;
        inv_nrm[1] = (b > 0.f) ? rsqrtf(b) : 0.f;
    }
}

// Per-node precompute, one wave per node. W columns live in VGPRs; the
// broadcast z[n][d] values are wave-uniform and read through the SCALAR
// path (readfirstlane(n) -> s_load), so the inner loop is pure
// v_fma_f32(v, s, v) with no ds_bpermute chain.
__global__ __launch_bounds__(256) void k_nodes(
        const float* __restrict__ z_in, const float* __restrict__ z_out,
        const float* __restrict__ z_self,
        const float* __restrict__ W_in, const float* __restrict__ b_in,
        const float* __restrict__ W_out, const float* __restrict__ b_out,
        const float* __restrict__ deg_out, const float* __restrict__ deg_in,
        const float* __restrict__ inv_nrm,
        _Float16* __restrict__ P_src, _Float16* __restrict__ P_dst,
        float* __restrict__ s_src, float* __restrict__ s_dst, int N) {
    const int lane = threadIdx.x & 63;
    const int gw0 = (blockIdx.x * blockDim.x + threadIdx.x) >> 6;
    const int nw = (gridDim.x * blockDim.x) >> 6;
    float wo[64], wi[64];
#pragma unroll
    for (int d = 0; d < 64; ++d) {
        wo[d] = W_out[d * 64 + lane];   // column `lane` of W_out
        wi[d] = W_in[d * 64 + lane];
    }
    const float bo = b_out[lane], bi = b_in[lane];
    const float inv0 = inv_nrm[0], inv1 = inv_nrm[1];
    for (int n0 = gw0; n0 < N; n0 += nw) {
        const int n = __builtin_amdgcn_readfirstlane(n0);   // wave-uniform
        const float* __restrict__ zro = z_out + (size_t)n * 65;
        const float* __restrict__ zri = z_in + (size_t)n * 65;
        const float zo = zro[lane];                  // per-lane (vector load)
        const float zi = zri[lane];
        const float zs = z_self[(size_t)n * 64 + lane];
        float ao = 0.f, ai = 0.f;
#pragma unroll
        for (int d = 0; d < 64; ++d) {               // zro[d]/zri[d]: s_load
            ao = fmaf(wo[d], zro[d], ao);
            ai = fmaf(wi[d], zri[d], ai);
        }
        P_src[(size_t)n * 128 + lane]      = (_Float16)ao;
        P_src[(size_t)n * 128 + 64 + lane] = (_Float16)zs;
        P_dst[(size_t)n * 128 + lane]      = (_Float16)zs;
        P_dst[(size_t)n * 128 + 64 + lane] = (_Float16)ai;
        float so = zo * bo, si = zi * bi;
#pragma unroll
        for (int off = 32; off; off >>= 1) {
            so += __shfl_xor(so, off);
            si += __shfl_xor(si, off);
        }
        if (lane == 0) {
            s_src[n] = BETA_C * fmaf(deg_out[n], inv0, zro[64])
                     + ALPHA_C * so;
            s_dst[n] = BETA_C * fmaf(deg_in[n], inv1, zri[64])
                     + ALPHA_C * si;
        }
    }
}

// Per-edge: 16 lanes/edge, one 128-length fp16 dot via two 16B gathers/lane.
__global__ __launch_bounds__(256) void k_edges(
        const int* __restrict__ eidx,
        const _Float16* __restrict__ P_src, const _Float16* __restrict__ P_dst,
        const float* __restrict__ s_src, const float* __restrict__ s_dst,
        float* __restrict__ out, int E) {
    const int sub = threadIdx.x & 15;
    const int e = blockIdx.x * (blockDim.x >> 4) + (threadIdx.x >> 4);
    if (e >= E) return;
    const int s = eidx[e];
    const int d = eidx[E + e];
    const half8 a = *(const half8*)(P_src + (size_t)s * 128 + sub * 8);
    const half8 b = *(const half8*)(P_dst + (size_t)d * 128 + sub * 8);
    float acc = 0.f;
#pragma unroll
    for (int j = 0; j < 8; ++j)
        acc = fmaf((float)a[j], (float)b[j], acc);
    acc += __shfl_xor(acc, 8);
    acc += __shfl_xor(acc, 4);
    acc += __shfl_xor(acc, 2);
    acc += __shfl_xor(acc, 1);
    if (sub == 0) {
        float v = fmaf(ALPHA_C, acc, s_src[s] + s_dst[d]);
        out[e] = 1.0f / (1.0f + __expf(-v));
    }
}

extern "C" void kernel_launch(void* const* d_in, const int* in_sizes, int n_in,
                              void* d_out, int out_size, void* d_ws, size_t ws_size,
                              hipStream_t stream) {
    const float* z_in   = (const float*)d_in[0];
    const float* z_out  = (const float*)d_in[1];
    const float* z_self = (const float*)d_in[2];
    const float* W_in   = (const float*)d_in[3];
    const float* b_in   = (const float*)d_in[4];
    const float* W_out  = (const float*)d_in[5];
    const float* b_out  = (const float*)d_in[6];
    const int*   eidx   = (const int*)d_in[7];

    const int N = in_sizes[2] / 64;   // z_self is [N, 64]
    const int E = in_sizes[7] / 2;    // edge_index is [2, E]

    float* ws       = (float*)d_ws;
    float* deg_out  = ws;                             // N
    float* deg_in   = ws + (size_t)N;                 // N
    float* s_src    = ws + 2 * (size_t)N;             // N
    float* s_dst    = ws + 3 * (size_t)N;             // N
    _Float16* P_src = (_Float16*)(ws + 4 * (size_t)N);        // N*128 fp16
    _Float16* P_dst = P_src + (size_t)N * 128;                // N*128 fp16
    float* partials = (float*)(P_dst + (size_t)N * 128);      // 2*NPART
    float* inv_nrm  = partials + 2 * NPART;                   // 2
    // Per-XCD partial histograms (8 x 2 x N u32 = 64N bytes) alias the P_src
    // region (512N bytes): dead by the time k_nodes writes P_src/P_dst.
    unsigned int* part = (unsigned int*)P_src;

    hipMemsetAsync(part, 0, (size_t)2 * NXCD * N * sizeof(unsigned int), stream);
    k_degrees<<<(E / 4 + 255) / 256, 256, 0, stream>>>(eidx, part, N, E);
    k_sumsq<<<NPART, 256, 0, stream>>>(part, deg_out, deg_in, partials, N);
    k_finish<<<1, 256, 0, stream>>>(partials, inv_nrm);
    k_nodes<<<1024, 256, 0, stream>>>(z_in, z_out, z_self, W_in, b_in, W_out, b_out,
                                      deg_out, deg_in, inv_nrm,
                                      P_src, P_dst, s_src, s_dst, N);
    k_edges<<<(E + 15) / 16, 256, 0, stream>>>(eidx, P_src, P_dst,
                                               s_src, s_dst, (float*)d_out, E);
}

// Round 5
// 263.036 us; speedup vs baseline: 2.1391x; 1.2914x over previous
//
#include <hip/hip_runtime.h>
#include <hip/hip_fp16.h>
#include <math.h>

#define ALPHA_C 0.5f
#define BETA_C  0.5f
#define NPART   256
#define NQUART  4

typedef _Float16 half8 __attribute__((ext_vector_type(8)));

// Exact degree histogram with NO global atomics.
// grid = (S slices, 2*NQUART roles). role = q*2 + dir. Each WG covers nodes
// [q*Q, q*Q+Q) for direction dir, over edge slice [s*chunk, (s+1)*chunk).
// Counters are packed u16 pairs in LDS (2 nodes / u32); per-slice counts are
// <= chunk < 65536 so no u16 overflow / cross-field carry is possible for ANY
// input. Flush is plain coalesced stores into per-(role,slice) scratch.
__global__ __launch_bounds__(256) void k_hist(
        const int* __restrict__ eidx, unsigned int* __restrict__ scr,
        int N, int E, int Q, int Wd, int chunk) {
    const int s = blockIdx.x;
    const int role = blockIdx.y;
    const int dir = role & 1;
    const int q = role >> 1;
    extern __shared__ unsigned int lds[];          // Wd words
    for (int w = threadIdx.x; w < Wd; w += blockDim.x) lds[w] = 0;
    __syncthreads();
    const int base = q * Q;
    const int hi = min(N - base, Q);               // nodes in this quarter
    const int* __restrict__ arr = eidx + (size_t)dir * E;
    const int start = s * chunk;
    const int end = min(E, start + chunk);
    // vector part (chunk % 4 == 0, so start % 4 == 0)
    const int4* __restrict__ a4 = (const int4*)arr;
    const int v1 = end >> 2;
    for (int v = (start >> 2) + threadIdx.x; v < v1; v += blockDim.x) {
        int4 x = a4[v];
        int l;
        l = x.x - base; if ((unsigned)l < (unsigned)hi) atomicAdd(&lds[l >> 1], 1u << ((l & 1) * 16));
        l = x.y - base; if ((unsigned)l < (unsigned)hi) atomicAdd(&lds[l >> 1], 1u << ((l & 1) * 16));
        l = x.z - base; if ((unsigned)l < (unsigned)hi) atomicAdd(&lds[l >> 1], 1u << ((l & 1) * 16));
        l = x.w - base; if ((unsigned)l < (unsigned)hi) atomicAdd(&lds[l >> 1], 1u << ((l & 1) * 16));
    }
    for (int i = (v1 << 2) + threadIdx.x; i < end; i += blockDim.x) {
        int l = arr[i] - base;
        if ((unsigned)l < (unsigned)hi) atomicAdd(&lds[l >> 1], 1u << ((l & 1) * 16));
    }
    __syncthreads();
    unsigned int* __restrict__ dst = scr + ((size_t)role * gridDim.x + s) * Wd;
    for (int w = threadIdx.x; w < Wd; w += blockDim.x) dst[w] = lds[w];
}

// Fold slice histograms -> float degrees + sum-of-squares partials.
__global__ __launch_bounds__(256) void k_fold(
        const unsigned int* __restrict__ scr,
        float* __restrict__ deg_out, float* __restrict__ deg_in,
        float* __restrict__ partials, int N, int Q, int Wd, int S) {
    float so = 0.f, si = 0.f;
    for (int n = blockIdx.x * blockDim.x + threadIdx.x; n < N;
         n += gridDim.x * blockDim.x) {
        const int q = n / Q, l = n - q * Q;
        const int w = l >> 1, sh = (l & 1) * 16;
        const unsigned int* __restrict__ p0 = scr + ((size_t)(q * 2 + 0) * S) * Wd + w;
        const unsigned int* __restrict__ p1 = scr + ((size_t)(q * 2 + 1) * S) * Wd + w;
        unsigned int a = 0, b = 0;
        for (int s = 0; s < S; ++s) {
            a += (p0[(size_t)s * Wd] >> sh) & 0xFFFFu;
            b += (p1[(size_t)s * Wd] >> sh) & 0xFFFFu;
        }
        float fa = (float)a, fb = (float)b;
        deg_out[n] = fa;
        deg_in[n] = fb;
        so = fmaf(fa, fa, so);
        si = fmaf(fb, fb, si);
    }
#pragma unroll
    for (int off = 32; off; off >>= 1) {
        so += __shfl_xor(so, off);
        si += __shfl_xor(si, off);
    }
    __shared__ float sm[2][4];
    int lane = threadIdx.x & 63, w = threadIdx.x >> 6;
    if (lane == 0) { sm[0][w] = so; sm[1][w] = si; }
    __syncthreads();
    if (threadIdx.x == 0) {
        partials[blockIdx.x]         = sm[0][0] + sm[0][1] + sm[0][2] + sm[0][3];
        partials[NPART + blockIdx.x] = sm[1][0] + sm[1][1] + sm[1][2] + sm[1][3];
    }
}

__global__ __launch_bounds__(256) void k_finish(
        const float* __restrict__ partials, float* __restrict__ inv_nrm) {
    int t = threadIdx.x;
    float so = partials[t], si = partials[NPART + t];
#pragma unroll
    for (int off = 32; off; off >>= 1) {
        so += __shfl_xor(so, off);
        si += __shfl_xor(si, off);
    }
    __shared__ float sm[2][4];
    int lane = t & 63, w = t >> 6;
    if (lane == 0) { sm[0][w] = so; sm[1][w] = si; }
    __syncthreads();
    if (t == 0) {
        float a = sm[0][0] + sm[0][1] + sm[0][2] + sm[0][3];
        float b = sm[1][0] + sm[1][1] + sm[1][2] + sm[1][3];
        inv_nrm[0] = (a > 0.f) ? rsqrtf(a) : 0.f;
        inv_nrm[1] = (b > 0.f) ? rsqrtf(b) : 0.f;
    }
}

// Per-node precompute, one wave per node. W columns live in VGPRs; the
// broadcast z[n][d] values are wave-uniform (readfirstlane(n)), read through
// the uniform path. 4 independent accumulators per matrix break the serial
// fma chain so load latency can be batched.
__global__ __launch_bounds__(256) void k_nodes(
        const float* __restrict__ z_in, const float* __restrict__ z_out,
        const float* __restrict__ z_self,
        const float* __restrict__ W_in, const float* __restrict__ b_in,
        const float* __restrict__ W_out, const float* __restrict__ b_out,
        const float* __restrict__ deg_out, const float* __restrict__ deg_in,
        const float* __restrict__ inv_nrm,
        _Float16* __restrict__ P_src, _Float16* __restrict__ P_dst,
        float* __restrict__ s_src, float* __restrict__ s_dst, int N) {
    const int lane = threadIdx.x & 63;
    const int gw0 = (blockIdx.x * blockDim.x + threadIdx.x) >> 6;
    const int nw = (gridDim.x * blockDim.x) >> 6;
    float wo[64], wi[64];
#pragma unroll
    for (int d = 0; d < 64; ++d) {
        wo[d] = W_out[d * 64 + lane];   // column `lane` of W_out
        wi[d] = W_in[d * 64 + lane];
    }
    const float bo = b_out[lane], bi = b_in[lane];
    const float inv0 = inv_nrm[0], inv1 = inv_nrm[1];
    for (int n0 = gw0; n0 < N; n0 += nw) {
        const int n = __builtin_amdgcn_readfirstlane(n0);   // wave-uniform
        const float* __restrict__ zro = z_out + (size_t)n * 65;
        const float* __restrict__ zri = z_in + (size_t)n * 65;
        const float zo = zro[lane];                  // per-lane (vector load)
        const float zi = zri[lane];
        const float zs = z_self[(size_t)n * 64 + lane];
        float ao0 = 0.f, ao1 = 0.f, ao2 = 0.f, ao3 = 0.f;
        float ai0 = 0.f, ai1 = 0.f, ai2 = 0.f, ai3 = 0.f;
#pragma unroll
        for (int d = 0; d < 64; d += 4) {            // uniform loads, 8 chains
            ao0 = fmaf(wo[d],     zro[d],     ao0);
            ao1 = fmaf(wo[d + 1], zro[d + 1], ao1);
            ao2 = fmaf(wo[d + 2], zro[d + 2], ao2);
            ao3 = fmaf(wo[d + 3], zro[d + 3], ao3);
            ai0 = fmaf(wi[d],     zri[d],     ai0);
            ai1 = fmaf(wi[d + 1], zri[d + 1], ai1);
            ai2 = fmaf(wi[d + 2], zri[d + 2], ai2);
            ai3 = fmaf(wi[d + 3], zri[d + 3], ai3);
        }
        const float ao = (ao0 + ao1) + (ao2 + ao3);
        const float ai = (ai0 + ai1) + (ai2 + ai3);
        P_src[(size_t)n * 128 + lane]      = (_Float16)ao;
        P_src[(size_t)n * 128 + 64 + lane] = (_Float16)zs;
        P_dst[(size_t)n * 128 + lane]      = (_Float16)zs;
        P_dst[(size_t)n * 128 + 64 + lane] = (_Float16)ai;
        float so = zo * bo, si = zi * bi;
#pragma unroll
        for (int off = 32; off; off >>= 1) {
            so += __shfl_xor(so, off);
            si += __shfl_xor(si, off);
        }
        if (lane == 0) {
            s_src[n] = BETA_C * fmaf(deg_out[n], inv0, zro[64])
                     + ALPHA_C * so;
            s_dst[n] = BETA_C * fmaf(deg_in[n], inv1, zri[64])
                     + ALPHA_C * si;
        }
    }
}

// Per-edge: 16 lanes/edge, one 128-length fp16 dot via two 16B gathers/lane.
__global__ __launch_bounds__(256) void k_edges(
        const int* __restrict__ eidx,
        const _Float16* __restrict__ P_src, const _Float16* __restrict__ P_dst,
        const float* __restrict__ s_src, const float* __restrict__ s_dst,
        float* __restrict__ out, int E) {
    const int sub = threadIdx.x & 15;
    const int e = blockIdx.x * (blockDim.x >> 4) + (threadIdx.x >> 4);
    if (e >= E) return;
    const int s = eidx[e];
    const int d = eidx[E + e];
    const half8 a = *(const half8*)(P_src + (size_t)s * 128 + sub * 8);
    const half8 b = *(const half8*)(P_dst + (size_t)d * 128 + sub * 8);
    float acc = 0.f;
#pragma unroll
    for (int j = 0; j < 8; ++j)
        acc = fmaf((float)a[j], (float)b[j], acc);
    acc += __shfl_xor(acc, 8);
    acc += __shfl_xor(acc, 4);
    acc += __shfl_xor(acc, 2);
    acc += __shfl_xor(acc, 1);
    if (sub == 0) {
        float v = fmaf(ALPHA_C, acc, s_src[s] + s_dst[d]);
        out[e] = 1.0f / (1.0f + __expf(-v));
    }
}

extern "C" void kernel_launch(void* const* d_in, const int* in_sizes, int n_in,
                              void* d_out, int out_size, void* d_ws, size_t ws_size,
                              hipStream_t stream) {
    const float* z_in   = (const float*)d_in[0];
    const float* z_out  = (const float*)d_in[1];
    const float* z_self = (const float*)d_in[2];
    const float* W_in   = (const float*)d_in[3];
    const float* b_in   = (const float*)d_in[4];
    const float* W_out  = (const float*)d_in[5];
    const float* b_out  = (const float*)d_in[6];
    const int*   eidx   = (const int*)d_in[7];

    const int N = in_sizes[2] / 64;   // z_self is [N, 64]
    const int E = in_sizes[7] / 2;    // edge_index is [2, E]

    // Histogram geometry: per-slice edge count < 65536 => u16-exact.
    const int Q = (N + NQUART - 1) / NQUART;          // nodes per quarter
    const int Wd = (Q + 1) / 2;                       // packed u32 words
    int S = (E + 49999) / 50000;                      // slices
    if (S < 1) S = 1;
    int chunk = ((E + S - 1) / S + 3) & ~3;           // mult of 4, < 65536

    float* ws       = (float*)d_ws;
    float* deg_out  = ws;                             // N
    float* deg_in   = ws + (size_t)N;                 // N
    float* s_src    = ws + 2 * (size_t)N;             // N
    float* s_dst    = ws + 3 * (size_t)N;             // N
    _Float16* P_src = (_Float16*)(ws + 4 * (size_t)N);        // N*128 fp16
    _Float16* P_dst = P_src + (size_t)N * 128;                // N*128 fp16
    float* partials = (float*)(P_dst + (size_t)N * 128);      // 2*NPART
    float* inv_nrm  = partials + 2 * NPART;                   // 2
    // Slice histograms (2*NQUART * S * Wd u32 ~= 12.8 MB) alias the P_src
    // region (25.6 MB): dead before k_nodes writes P_src/P_dst.
    unsigned int* scr = (unsigned int*)P_src;

    dim3 hgrid(S, 2 * NQUART);
    k_hist<<<hgrid, 256, (size_t)Wd * 4, stream>>>(eidx, scr, N, E, Q, Wd, chunk);
    k_fold<<<NPART, 256, 0, stream>>>(scr, deg_out, deg_in, partials, N, Q, Wd, S);
    k_finish<<<1, 256, 0, stream>>>(partials, inv_nrm);
    k_nodes<<<1024, 256, 0, stream>>>(z_in, z_out, z_self, W_in, b_in, W_out, b_out,
                                      deg_out, deg_in, inv_nrm,
                                      P_src, P_dst, s_src, s_dst, N);
    k_edges<<<(E + 15) / 16, 256, 0, stream>>>(eidx, P_src, P_dst,
                                               s_src, s_dst, (float*)d_out, E);
}

// Round 6
// 252.184 us; speedup vs baseline: 2.2312x; 1.0430x over previous
//
#include <hip/hip_runtime.h>
#include <hip/hip_fp16.h>
#include <math.h>

#define ALPHA_C 0.5f
#define BETA_C  0.5f
#define NPART   256
#define NQUART  4

typedef _Float16 half8 __attribute__((ext_vector_type(8)));
typedef float f32x4 __attribute__((ext_vector_type(4)));

// Exact degree histogram with NO global atomics (see round-4 notes).
__global__ __launch_bounds__(256) void k_hist(
        const int* __restrict__ eidx, unsigned int* __restrict__ scr,
        int N, int E, int Q, int Wd, int chunk) {
    const int s = blockIdx.x;
    const int role = blockIdx.y;
    const int dir = role & 1;
    const int q = role >> 1;
    extern __shared__ unsigned int lds[];          // Wd words
    for (int w = threadIdx.x; w < Wd; w += blockDim.x) lds[w] = 0;
    __syncthreads();
    const int base = q * Q;
    const int hi = min(N - base, Q);               // nodes in this quarter
    const int* __restrict__ arr = eidx + (size_t)dir * E;
    const int start = s * chunk;
    const int end = min(E, start + chunk);
    const int4* __restrict__ a4 = (const int4*)arr;
    const int v1 = end >> 2;
    for (int v = (start >> 2) + threadIdx.x; v < v1; v += blockDim.x) {
        int4 x = a4[v];
        int l;
        l = x.x - base; if ((unsigned)l < (unsigned)hi) atomicAdd(&lds[l >> 1], 1u << ((l & 1) * 16));
        l = x.y - base; if ((unsigned)l < (unsigned)hi) atomicAdd(&lds[l >> 1], 1u << ((l & 1) * 16));
        l = x.z - base; if ((unsigned)l < (unsigned)hi) atomicAdd(&lds[l >> 1], 1u << ((l & 1) * 16));
        l = x.w - base; if ((unsigned)l < (unsigned)hi) atomicAdd(&lds[l >> 1], 1u << ((l & 1) * 16));
    }
    for (int i = (v1 << 2) + threadIdx.x; i < end; i += blockDim.x) {
        int l = arr[i] - base;
        if ((unsigned)l < (unsigned)hi) atomicAdd(&lds[l >> 1], 1u << ((l & 1) * 16));
    }
    __syncthreads();
    unsigned int* __restrict__ dst = scr + ((size_t)role * gridDim.x + s) * Wd;
    for (int w = threadIdx.x; w < Wd; w += blockDim.x) dst[w] = lds[w];
}

// Fold slice histograms -> float degrees + sum-of-squares partials.
__global__ __launch_bounds__(256) void k_fold(
        const unsigned int* __restrict__ scr,
        float* __restrict__ deg_out, float* __restrict__ deg_in,
        float* __restrict__ partials, int N, int Q, int Wd, int S) {
    float so = 0.f, si = 0.f;
    for (int n = blockIdx.x * blockDim.x + threadIdx.x; n < N;
         n += gridDim.x * blockDim.x) {
        const int q = n / Q, l = n - q * Q;
        const int w = l >> 1, sh = (l & 1) * 16;
        const unsigned int* __restrict__ p0 = scr + ((size_t)(q * 2 + 0) * S) * Wd + w;
        const unsigned int* __restrict__ p1 = scr + ((size_t)(q * 2 + 1) * S) * Wd + w;
        unsigned int a = 0, b = 0;
        for (int s = 0; s < S; ++s) {
            a += (p0[(size_t)s * Wd] >> sh) & 0xFFFFu;
            b += (p1[(size_t)s * Wd] >> sh) & 0xFFFFu;
        }
        float fa = (float)a, fb = (float)b;
        deg_out[n] = fa;
        deg_in[n] = fb;
        so = fmaf(fa, fa, so);
        si = fmaf(fb, fb, si);
    }
#pragma unroll
    for (int off = 32; off; off >>= 1) {
        so += __shfl_xor(so, off);
        si += __shfl_xor(si, off);
    }
    __shared__ float sm[2][4];
    int lane = threadIdx.x & 63, w = threadIdx.x >> 6;
    if (lane == 0) { sm[0][w] = so; sm[1][w] = si; }
    __syncthreads();
    if (threadIdx.x == 0) {
        partials[blockIdx.x]         = sm[0][0] + sm[0][1] + sm[0][2] + sm[0][3];
        partials[NPART + blockIdx.x] = sm[1][0] + sm[1][1] + sm[1][2] + sm[1][3];
    }
}

__global__ __launch_bounds__(256) void k_finish(
        const float* __restrict__ partials, float* __restrict__ inv_nrm) {
    int t = threadIdx.x;
    float so = partials[t], si = partials[NPART + t];
#pragma unroll
    for (int off = 32; off; off >>= 1) {
        so += __shfl_xor(so, off);
        si += __shfl_xor(si, off);
    }
    __shared__ float sm[2][4];
    int lane = t & 63, w = t >> 6;
    if (lane == 0) { sm[0][w] = so; sm[1][w] = si; }
    __syncthreads();
    if (t == 0) {
        float a = sm[0][0] + sm[0][1] + sm[0][2] + sm[0][3];
        float b = sm[1][0] + sm[1][1] + sm[1][2] + sm[1][3];
        inv_nrm[0] = (a > 0.f) ? rsqrtf(a) : 0.f;
        inv_nrm[1] = (b > 0.f) ? rsqrtf(b) : 0.f;
    }
}

// MFMA node precompute. Per wave: 16 nodes x 64 outputs for BOTH weight
// matrices via v_mfma_f32_16x16x32_f16; the b-bias dots ride along as a 5th
// B-tile whose only nonzero column is b. Fragment maps (16x16x32):
//   A[m][k]: m = lane&15, k = 8*(lane>>4)+j   (j = 0..7)
//   B[k][n]: n = lane&15, k = 8*(lane>>4)+j
//   D[m][n]: n = lane&15, m = 4*(lane>>4)+reg  (m89-verified)
__global__ __launch_bounds__(256) void k_nodes(
        const float* __restrict__ z_in, const float* __restrict__ z_out,
        const float* __restrict__ z_self,
        const float* __restrict__ W_in, const float* __restrict__ b_in,
        const float* __restrict__ W_out, const float* __restrict__ b_out,
        const float* __restrict__ deg_out, const float* __restrict__ deg_in,
        const float* __restrict__ inv_nrm,
        _Float16* __restrict__ P_src, _Float16* __restrict__ P_dst,
        float* __restrict__ s_src, float* __restrict__ s_dst, int N) {
    const int lane = threadIdx.x & 63;
    const int wid  = threadIdx.x >> 6;
    const int r = lane & 15, g = lane >> 4;
    const int base = blockIdx.x * 64 + wid * 16;
    if (base >= N) return;

    // --- B fragments (held in VGPRs for the whole kernel) ---
    half8 BO[2][4], BI[2][4], bO[2], bI[2];
#pragma unroll
    for (int s = 0; s < 2; ++s) {
#pragma unroll
        for (int t = 0; t < 4; ++t) {
#pragma unroll
            for (int j = 0; j < 8; ++j) {
                const int k = 32 * s + 8 * g + j;
                BO[s][t][j] = (_Float16)W_out[k * 64 + 16 * t + r];
                BI[s][t][j] = (_Float16)W_in [k * 64 + 16 * t + r];
            }
        }
#pragma unroll
        for (int j = 0; j < 8; ++j) {
            const int k = 32 * s + 8 * g + j;
            bO[s][j] = (r == 0) ? (_Float16)b_out[k] : (_Float16)0.f;
            bI[s][j] = (r == 0) ? (_Float16)b_in [k] : (_Float16)0.f;
        }
    }

    // --- A fragments: this wave's 16 z rows (row clamped for tail) ---
    const int row = min(base + r, N - 1);
    const float* __restrict__ zo_row = z_out + (size_t)row * 65;
    const float* __restrict__ zi_row = z_in  + (size_t)row * 65;
    half8 AO[2], AI[2];
#pragma unroll
    for (int s = 0; s < 2; ++s)
#pragma unroll
        for (int j = 0; j < 8; ++j) {
            AO[s][j] = (_Float16)zo_row[32 * s + 8 * g + j];
            AI[s][j] = (_Float16)zi_row[32 * s + 8 * g + j];
        }

    f32x4 aO[4], aI[4], abO, abI;
#pragma unroll
    for (int t = 0; t < 4; ++t) { aO[t] = (f32x4)0.f; aI[t] = (f32x4)0.f; }
    abO = (f32x4)0.f; abI = (f32x4)0.f;
#pragma unroll
    for (int s = 0; s < 2; ++s) {
#pragma unroll
        for (int t = 0; t < 4; ++t) {
            aO[t] = __builtin_amdgcn_mfma_f32_16x16x32_f16(AO[s], BO[s][t], aO[t], 0, 0, 0);
            aI[t] = __builtin_amdgcn_mfma_f32_16x16x32_f16(AI[s], BI[s][t], aI[t], 0, 0, 0);
        }
        abO = __builtin_amdgcn_mfma_f32_16x16x32_f16(AO[s], bO[s], abO, 0, 0, 0);
        abI = __builtin_amdgcn_mfma_f32_16x16x32_f16(AI[s], bI[s], abI, 0, 0, 0);
    }

    // --- epilogue: v_out -> P_src[:,0:64], v_in -> P_dst[:,64:128] ---
#pragma unroll
    for (int t = 0; t < 4; ++t)
#pragma unroll
        for (int rr = 0; rr < 4; ++rr) {
            const int m = base + 4 * g + rr;
            if (m < N) {
                P_src[(size_t)m * 128 + 16 * t + r]      = (_Float16)aO[t][rr];
                P_dst[(size_t)m * 128 + 64 + 16 * t + r] = (_Float16)aI[t][rr];
            }
        }

    // per-node scalars from the bias-dot accumulators (col 0 lanes only)
    if (r == 0) {
        const float i0 = inv_nrm[0], i1 = inv_nrm[1];
#pragma unroll
        for (int rr = 0; rr < 4; ++rr) {
            const int m = base + 4 * g + rr;
            if (m < N) {
                s_src[m] = BETA_C * fmaf(deg_out[m], i0, z_out[(size_t)m * 65 + 64])
                         + ALPHA_C * abO[rr];
                s_dst[m] = BETA_C * fmaf(deg_in[m],  i1, z_in [(size_t)m * 65 + 64])
                         + ALPHA_C * abI[rr];
            }
        }
    }

    // z_self pack (f16) into both P halves, coalesced per row
#pragma unroll
    for (int it = 0; it < 16; ++it) {
        const int m = base + it;
        if (m < N) {
            const _Float16 v = (_Float16)z_self[(size_t)m * 64 + lane];
            P_src[(size_t)m * 128 + 64 + lane] = v;
            P_dst[(size_t)m * 128 + lane]      = v;
        }
    }
}

// Per-edge: 16 lanes/edge, one 128-length fp16 dot via two 16B gathers/lane.
__global__ __launch_bounds__(256) void k_edges(
        const int* __restrict__ eidx,
        const _Float16* __restrict__ P_src, const _Float16* __restrict__ P_dst,
        const float* __restrict__ s_src, const float* __restrict__ s_dst,
        float* __restrict__ out, int E) {
    const int sub = threadIdx.x & 15;
    const int e = blockIdx.x * (blockDim.x >> 4) + (threadIdx.x >> 4);
    if (e >= E) return;
    const int s = eidx[e];
    const int d = eidx[E + e];
    const half8 a = *(const half8*)(P_src + (size_t)s * 128 + sub * 8);
    const half8 b = *(const half8*)(P_dst + (size_t)d * 128 + sub * 8);
    float acc = 0.f;
#pragma unroll
    for (int j = 0; j < 8; ++j)
        acc = fmaf((float)a[j], (float)b[j], acc);
    acc += __shfl_xor(acc, 8);
    acc += __shfl_xor(acc, 4);
    acc += __shfl_xor(acc, 2);
    acc += __shfl_xor(acc, 1);
    if (sub == 0) {
        float v = fmaf(ALPHA_C, acc, s_src[s] + s_dst[d]);
        out[e] = 1.0f / (1.0f + __expf(-v));
    }
}

extern "C" void kernel_launch(void* const* d_in, const int* in_sizes, int n_in,
                              void* d_out, int out_size, void* d_ws, size_t ws_size,
                              hipStream_t stream) {
    const float* z_in   = (const float*)d_in[0];
    const float* z_out  = (const float*)d_in[1];
    const float* z_self = (const float*)d_in[2];
    const float* W_in   = (const float*)d_in[3];
    const float* b_in   = (const float*)d_in[4];
    const float* W_out  = (const float*)d_in[5];
    const float* b_out  = (const float*)d_in[6];
    const int*   eidx   = (const int*)d_in[7];

    const int N = in_sizes[2] / 64;   // z_self is [N, 64]
    const int E = in_sizes[7] / 2;    // edge_index is [2, E]

    // Histogram geometry: per-slice edge count < 65536 => u16-exact.
    const int Q = (N + NQUART - 1) / NQUART;          // nodes per quarter
    const int Wd = (Q + 1) / 2;                       // packed u32 words
    int S = (E + 49999) / 50000;                      // slices
    if (S < 1) S = 1;
    int chunk = ((E + S - 1) / S + 3) & ~3;           // mult of 4, < 65536

    float* ws       = (float*)d_ws;
    float* deg_out  = ws;                             // N
    float* deg_in   = ws + (size_t)N;                 // N
    float* s_src    = ws + 2 * (size_t)N;             // N
    float* s_dst    = ws + 3 * (size_t)N;             // N
    _Float16* P_src = (_Float16*)(ws + 4 * (size_t)N);        // N*128 fp16
    _Float16* P_dst = P_src + (size_t)N * 128;                // N*128 fp16
    float* partials = (float*)(P_dst + (size_t)N * 128);      // 2*NPART
    float* inv_nrm  = partials + 2 * NPART;                   // 2
    // Slice histograms (~12.8 MB) alias the P_src region (25.6 MB): dead
    // before k_nodes writes P_src/P_dst.
    unsigned int* scr = (unsigned int*)P_src;

    dim3 hgrid(S, 2 * NQUART);
    k_hist<<<hgrid, 256, (size_t)Wd * 4, stream>>>(eidx, scr, N, E, Q, Wd, chunk);
    k_fold<<<NPART, 256, 0, stream>>>(scr, deg_out, deg_in, partials, N, Q, Wd, S);
    k_finish<<<1, 256, 0, stream>>>(partials, inv_nrm);
    k_nodes<<<(N + 63) / 64, 256, 0, stream>>>(z_in, z_out, z_self, W_in, b_in,
                                               W_out, b_out, deg_out, deg_in,
                                               inv_nrm, P_src, P_dst,
                                               s_src, s_dst, N);
    k_edges<<<(E + 15) / 16, 256, 0, stream>>>(eidx, P_src, P_dst,
                                               s_src, s_dst, (float*)d_out, E);
}

// Round 7
// 205.803 us; speedup vs baseline: 2.7340x; 1.2254x over previous
//
#include <hip/hip_runtime.h>
#include <hip/hip_fp16.h>
#include <math.h>

#define ALPHA_C 0.5f
#define BETA_C  0.5f
#define NPART   256
#define NQUART  4

typedef _Float16 half8 __attribute__((ext_vector_type(8)));
typedef _Float16 half2v __attribute__((ext_vector_type(2)));
typedef float f32x4 __attribute__((ext_vector_type(4)));

// XOR row-swizzle: spreads a column access across 8 LDS bank-groups.
__device__ __forceinline__ int swz(int row, int byteoff) {
    return byteoff ^ ((row & 7) << 4);
}

// Exact degree histogram with NO global atomics (see round-4 notes).
__global__ __launch_bounds__(256) void k_hist(
        const int* __restrict__ eidx, unsigned int* __restrict__ scr,
        int N, int E, int Q, int Wd, int chunk) {
    const int s = blockIdx.x;
    const int role = blockIdx.y;
    const int dir = role & 1;
    const int q = role >> 1;
    extern __shared__ unsigned int lds[];          // Wd words
    for (int w = threadIdx.x; w < Wd; w += blockDim.x) lds[w] = 0;
    __syncthreads();
    const int base = q * Q;
    const int hi = min(N - base, Q);               // nodes in this quarter
    const int* __restrict__ arr = eidx + (size_t)dir * E;
    const int start = s * chunk;
    const int end = min(E, start + chunk);
    const int4* __restrict__ a4 = (const int4*)arr;
    const int v1 = end >> 2;
    for (int v = (start >> 2) + threadIdx.x; v < v1; v += blockDim.x) {
        int4 x = a4[v];
        int l;
        l = x.x - base; if ((unsigned)l < (unsigned)hi) atomicAdd(&lds[l >> 1], 1u << ((l & 1) * 16));
        l = x.y - base; if ((unsigned)l < (unsigned)hi) atomicAdd(&lds[l >> 1], 1u << ((l & 1) * 16));
        l = x.z - base; if ((unsigned)l < (unsigned)hi) atomicAdd(&lds[l >> 1], 1u << ((l & 1) * 16));
        l = x.w - base; if ((unsigned)l < (unsigned)hi) atomicAdd(&lds[l >> 1], 1u << ((l & 1) * 16));
    }
    for (int i = (v1 << 2) + threadIdx.x; i < end; i += blockDim.x) {
        int l = arr[i] - base;
        if ((unsigned)l < (unsigned)hi) atomicAdd(&lds[l >> 1], 1u << ((l & 1) * 16));
    }
    __syncthreads();
    unsigned int* __restrict__ dst = scr + ((size_t)role * gridDim.x + s) * Wd;
    for (int w = threadIdx.x; w < Wd; w += blockDim.x) dst[w] = lds[w];
}

// Fold slice histograms -> float degrees + sum-of-squares partials.
__global__ __launch_bounds__(256) void k_fold(
        const unsigned int* __restrict__ scr,
        float* __restrict__ deg_out, float* __restrict__ deg_in,
        float* __restrict__ partials, int N, int Q, int Wd, int S) {
    float so = 0.f, si = 0.f;
    for (int n = blockIdx.x * blockDim.x + threadIdx.x; n < N;
         n += gridDim.x * blockDim.x) {
        const int q = n / Q, l = n - q * Q;
        const int w = l >> 1, sh = (l & 1) * 16;
        const unsigned int* __restrict__ p0 = scr + ((size_t)(q * 2 + 0) * S) * Wd + w;
        const unsigned int* __restrict__ p1 = scr + ((size_t)(q * 2 + 1) * S) * Wd + w;
        unsigned int a = 0, b = 0;
        for (int s = 0; s < S; ++s) {
            a += (p0[(size_t)s * Wd] >> sh) & 0xFFFFu;
            b += (p1[(size_t)s * Wd] >> sh) & 0xFFFFu;
        }
        float fa = (float)a, fb = (float)b;
        deg_out[n] = fa;
        deg_in[n] = fb;
        so = fmaf(fa, fa, so);
        si = fmaf(fb, fb, si);
    }
#pragma unroll
    for (int off = 32; off; off >>= 1) {
        so += __shfl_xor(so, off);
        si += __shfl_xor(si, off);
    }
    __shared__ float sm[2][4];
    int lane = threadIdx.x & 63, w = threadIdx.x >> 6;
    if (lane == 0) { sm[0][w] = so; sm[1][w] = si; }
    __syncthreads();
    if (threadIdx.x == 0) {
        partials[blockIdx.x]         = sm[0][0] + sm[0][1] + sm[0][2] + sm[0][3];
        partials[NPART + blockIdx.x] = sm[1][0] + sm[1][1] + sm[1][2] + sm[1][3];
    }
}

__global__ __launch_bounds__(256) void k_finish(
        const float* __restrict__ partials, float* __restrict__ inv_nrm) {
    int t = threadIdx.x;
    float so = partials[t], si = partials[NPART + t];
#pragma unroll
    for (int off = 32; off; off >>= 1) {
        so += __shfl_xor(so, off);
        si += __shfl_xor(si, off);
    }
    __shared__ float sm[2][4];
    int lane = t & 63, w = t >> 6;
    if (lane == 0) { sm[0][w] = so; sm[1][w] = si; }
    __syncthreads();
    if (t == 0) {
        float a = sm[0][0] + sm[0][1] + sm[0][2] + sm[0][3];
        float b = sm[1][0] + sm[1][1] + sm[1][2] + sm[1][3];
        inv_nrm[0] = (a > 0.f) ? rsqrtf(a) : 0.f;
        inv_nrm[1] = (b > 0.f) ? rsqrtf(b) : 0.f;
    }
}

// MFMA node precompute, LDS-staged. Per block: 64 nodes, 4 waves x 16 nodes.
// Fragment maps (16x16x32, m89-verified, identical math to round 6):
//   A[m][k]: m = lane&15, k = 32*s + 8*(lane>>4) + j
//   B[k][n]: n = lane&15, k = 32*s + 8*(lane>>4) + j   (B = W^T, i.e. W[k][n])
//   D[m][n]: n = lane&15, m = 4*(lane>>4) + reg
// All LDS tiles use the (row&7)<<4 byte XOR swizzle on write AND read.
__global__ __launch_bounds__(256) void k_nodes(
        const float* __restrict__ z_in, const float* __restrict__ z_out,
        const float* __restrict__ z_self,
        const float* __restrict__ W_in, const float* __restrict__ b_in,
        const float* __restrict__ W_out, const float* __restrict__ b_out,
        const float* __restrict__ deg_out, const float* __restrict__ deg_in,
        const float* __restrict__ inv_nrm,
        _Float16* __restrict__ P_src, _Float16* __restrict__ P_dst,
        float* __restrict__ s_src, float* __restrict__ s_dst, int N) {
    __shared__ _Float16 smem[16384];                 // 32 KB
    char* lzo = (char*)smem;                         // [64][64] f16, 8 KB
    char* lzi = (char*)smem + 8192;
    char* lwo = (char*)smem + 16384;                 // W^T [n=64][k=64] f16
    char* lwi = (char*)smem + 24576;
    char* lps = (char*)smem;                         // [64][128] f16 (aliases)
    char* lpd = (char*)smem + 16384;

    const int tid = threadIdx.x;
    const int lane = tid & 63;
    const int wid = tid >> 6;
    const int r = lane & 15, g = lane >> 4;
    const int base = blockIdx.x * 64;
    const int wrow = wid * 16;

    // ---- phase 1: stage z tiles and W^T into LDS (coalesced reads) ----
#pragma unroll
    for (int it = 0; it < 8; ++it) {
        int flat = it * 256 + tid;                   // [0, 2048)
        int row = flat >> 5;                         // 0..63
        int c2 = (flat & 31) * 2;                    // even col
        int grow = min(base + row, N - 1);
        const float* zr = z_out + (size_t)grow * 65;
        half2v ho = { (_Float16)zr[c2], (_Float16)zr[c2 + 1] };
        *(half2v*)(lzo + row * 128 + swz(row, c2 * 2)) = ho;
        const float* zr2 = z_in + (size_t)grow * 65;
        half2v hi = { (_Float16)zr2[c2], (_Float16)zr2[c2 + 1] };
        *(half2v*)(lzi + row * 128 + swz(row, c2 * 2)) = hi;
    }
#pragma unroll
    for (int it = 0; it < 16; ++it) {
        int flat = it * 256 + tid;                   // [0, 4096)
        int k = flat >> 6, n = flat & 63;
        *(_Float16*)(lwo + n * 128 + swz(n, k * 2)) = (_Float16)W_out[k * 64 + n];
        *(_Float16*)(lwi + n * 128 + swz(n, k * 2)) = (_Float16)W_in [k * 64 + n];
    }
    // bias fragments (tiny, L2-hot, only col-0 lanes nonzero)
    half8 bO[2], bI[2];
#pragma unroll
    for (int s = 0; s < 2; ++s)
#pragma unroll
        for (int j = 0; j < 8; ++j) {
            int k = 32 * s + 8 * g + j;
            bO[s][j] = (r == 0) ? (_Float16)b_out[k] : (_Float16)0.f;
            bI[s][j] = (r == 0) ? (_Float16)b_in [k] : (_Float16)0.f;
        }
    __syncthreads();

    // ---- phase 2: fragments from LDS + MFMA ----
    half8 AO[2], AI[2];
#pragma unroll
    for (int s = 0; s < 2; ++s) {
        int arow = wrow + r;
        int off = arow * 128 + swz(arow, s * 64 + g * 16);
        AO[s] = *(half8*)(lzo + off);
        AI[s] = *(half8*)(lzi + off);
    }
    f32x4 aO[4], aI[4], abO = (f32x4)0.f, abI = (f32x4)0.f;
#pragma unroll
    for (int t = 0; t < 4; ++t) { aO[t] = (f32x4)0.f; aI[t] = (f32x4)0.f; }
#pragma unroll
    for (int s = 0; s < 2; ++s) {
#pragma unroll
        for (int t = 0; t < 4; ++t) {
            int n = 16 * t + r;
            int off = n * 128 + swz(n, s * 64 + g * 16);
            half8 BO = *(half8*)(lwo + off);
            aO[t] = __builtin_amdgcn_mfma_f32_16x16x32_f16(AO[s], BO, aO[t], 0, 0, 0);
            half8 BI = *(half8*)(lwi + off);
            aI[t] = __builtin_amdgcn_mfma_f32_16x16x32_f16(AI[s], BI, aI[t], 0, 0, 0);
        }
        abO = __builtin_amdgcn_mfma_f32_16x16x32_f16(AO[s], bO[s], abO, 0, 0, 0);
        abI = __builtin_amdgcn_mfma_f32_16x16x32_f16(AI[s], bI[s], abI, 0, 0, 0);
    }
    __syncthreads();   // lz/lw dead; lp aliases them

    // ---- phase 3: results + z_self into swizzled LDS P-tiles ----
#pragma unroll
    for (int t = 0; t < 4; ++t)
#pragma unroll
        for (int rr = 0; rr < 4; ++rr) {
            int lrow = wrow + 4 * g + rr;
            int col2 = (16 * t + r) * 2;
            *(_Float16*)(lps + lrow * 256 + swz(lrow, col2)) = (_Float16)aO[t][rr];
            *(_Float16*)(lpd + lrow * 256 + swz(lrow, 128 + col2)) = (_Float16)aI[t][rr];
        }
#pragma unroll
    for (int it = 0; it < 8; ++it) {
        int flat = it * 256 + tid;
        int row = flat >> 5;
        int c2 = (flat & 31) * 2;
        int grow = min(base + row, N - 1);
        float2 v = *(const float2*)(z_self + (size_t)grow * 64 + c2);
        half2v h = { (_Float16)v.x, (_Float16)v.y };
        *(half2v*)(lps + row * 256 + swz(row, 128 + c2 * 2)) = h;   // P_src[,64:]
        *(half2v*)(lpd + row * 256 + swz(row, c2 * 2)) = h;         // P_dst[,:64]
    }
    // per-node scalars from the bias-dot accumulators (col-0 lanes)
    if (r == 0) {
        const float i0 = inv_nrm[0], i1 = inv_nrm[1];
#pragma unroll
        for (int rr = 0; rr < 4; ++rr) {
            int m = base + wrow + 4 * g + rr;
            if (m < N) {
                s_src[m] = BETA_C * fmaf(deg_out[m], i0, z_out[(size_t)m * 65 + 64])
                         + ALPHA_C * abO[rr];
                s_dst[m] = BETA_C * fmaf(deg_in[m],  i1, z_in [(size_t)m * 65 + 64])
                         + ALPHA_C * abI[rr];
            }
        }
    }
    __syncthreads();

    // ---- phase 4: coalesced 16B/lane flush to global ----
#pragma unroll
    for (int it = 0; it < 4; ++it) {
        int lrow = it * 16 + (tid >> 4);
        int seg = tid & 15;
        int m = base + lrow;
        if (m < N) {
            half8 v = *(half8*)(lps + lrow * 256 + swz(lrow, seg * 16));
            *(half8*)(P_src + (size_t)m * 128 + seg * 8) = v;
            half8 v2 = *(half8*)(lpd + lrow * 256 + swz(lrow, seg * 16));
            *(half8*)(P_dst + (size_t)m * 128 + seg * 8) = v2;
        }
    }
}

// Per-edge: 16 lanes/edge, one 128-length fp16 dot via two 16B gathers/lane.
__global__ __launch_bounds__(256) void k_edges(
        const int* __restrict__ eidx,
        const _Float16* __restrict__ P_src, const _Float16* __restrict__ P_dst,
        const float* __restrict__ s_src, const float* __restrict__ s_dst,
        float* __restrict__ out, int E) {
    const int sub = threadIdx.x & 15;
    const int e = blockIdx.x * (blockDim.x >> 4) + (threadIdx.x >> 4);
    if (e >= E) return;
    const int s = eidx[e];
    const int d = eidx[E + e];
    const half8 a = *(const half8*)(P_src + (size_t)s * 128 + sub * 8);
    const half8 b = *(const half8*)(P_dst + (size_t)d * 128 + sub * 8);
    float acc = 0.f;
#pragma unroll
    for (int j = 0; j < 8; ++j)
        acc = fmaf((float)a[j], (float)b[j], acc);
    acc += __shfl_xor(acc, 8);
    acc += __shfl_xor(acc, 4);
    acc += __shfl_xor(acc, 2);
    acc += __shfl_xor(acc, 1);
    if (sub == 0) {
        float v = fmaf(ALPHA_C, acc, s_src[s] + s_dst[d]);
        out[e] = 1.0f / (1.0f + __expf(-v));
    }
}

extern "C" void kernel_launch(void* const* d_in, const int* in_sizes, int n_in,
                              void* d_out, int out_size, void* d_ws, size_t ws_size,
                              hipStream_t stream) {
    const float* z_in   = (const float*)d_in[0];
    const float* z_out  = (const float*)d_in[1];
    const float* z_self = (const float*)d_in[2];
    const float* W_in   = (const float*)d_in[3];
    const float* b_in   = (const float*)d_in[4];
    const float* W_out  = (const float*)d_in[5];
    const float* b_out  = (const float*)d_in[6];
    const int*   eidx   = (const int*)d_in[7];

    const int N = in_sizes[2] / 64;   // z_self is [N, 64]
    const int E = in_sizes[7] / 2;    // edge_index is [2, E]

    // Histogram geometry: per-slice edge count < 65536 => u16-exact.
    const int Q = (N + NQUART - 1) / NQUART;          // nodes per quarter
    const int Wd = (Q + 1) / 2;                       // packed u32 words
    int S = (E + 49999) / 50000;                      // slices
    if (S < 1) S = 1;
    int chunk = ((E + S - 1) / S + 3) & ~3;           // mult of 4, < 65536

    float* ws       = (float*)d_ws;
    float* deg_out  = ws;                             // N
    float* deg_in   = ws + (size_t)N;                 // N
    float* s_src    = ws + 2 * (size_t)N;             // N
    float* s_dst    = ws + 3 * (size_t)N;             // N
    _Float16* P_src = (_Float16*)(ws + 4 * (size_t)N);        // N*128 fp16
    _Float16* P_dst = P_src + (size_t)N * 128;                // N*128 fp16
    float* partials = (float*)(P_dst + (size_t)N * 128);      // 2*NPART
    float* inv_nrm  = partials + 2 * NPART;                   // 2
    // Slice histograms (~12.8 MB) alias the P_src region (25.6 MB): dead
    // before k_nodes writes P_src/P_dst.
    unsigned int* scr = (unsigned int*)P_src;

    dim3 hgrid(S, 2 * NQUART);
    k_hist<<<hgrid, 256, (size_t)Wd * 4, stream>>>(eidx, scr, N, E, Q, Wd, chunk);
    k_fold<<<NPART, 256, 0, stream>>>(scr, deg_out, deg_in, partials, N, Q, Wd, S);
    k_finish<<<1, 256, 0, stream>>>(partials, inv_nrm);
    k_nodes<<<(N + 63) / 64, 256, 0, stream>>>(z_in, z_out, z_self, W_in, b_in,
                                               W_out, b_out, deg_out, deg_in,
                                               inv_nrm, P_src, P_dst,
                                               s_src, s_dst, N);
    k_edges<<<(E + 15) / 16, 256, 0, stream>>>(eidx, P_src, P_dst,
                                               s_src, s_dst, (float*)d_out, E);
}